// Round 2
// baseline (109.473 us; speedup 1.0000x reference)
//
#include <hip/hip_runtime.h>
#include <math.h>

// Problem constants (match reference setup_inputs)
#define BB 4
#define NN 16384
#define MM 2048
#define BM (BB*MM)      // 8192  (sample queries)
#define BN (BB*NN)      // 65536 (xyz queries)

#define TGT 256         // targets per k_min block (1 KB staged -> 4 KB float4 LDS)
#define S1  64          // dir1 (smp->xyz) target splits: 64*256 = NN
#define S2  8           // dir2 (xyz->smp) target splits: 8*256  = MM

// Workspace layout (floats). Every slot plain-stored by exactly one owner
// before being read -> no init kernel. R_CNT zeroed by k_min block 0.
#define PART1OFF 0                       // [S1*BM] dir1 partial mins (incl qsq)
#define PART2OFF (S1*BM)                 // [S2*BN] dir2 partial mins (incl qsq)
#define REDOFF   (PART1OFF + S1*BM + S2*BN)
#define R_SUMS1  (REDOFF)                // [32]  per-block sums of d_smp_org
#define R_MAXES  (REDOFF+32)             // [32]  per-block maxes (8 blocks/batch)
#define R_SUMS2  (REDOFF+64)             // [128] per-block sums of d_org_smp
#define R_GST    (REDOFF+192)            // [32]  trans partial sums
#define R_GSR    (REDOFF+224)            // [32]  rot partial sums
#define R_GSC    (REDOFF+256)            // [32]  cls partial sums
#define R_CNT    (REDOFF+288)            // [1]   k_reduce completion counter

__device__ __forceinline__ float blockSum256(float v, volatile float* s4) {
#pragma unroll
    for (int o = 32; o > 0; o >>= 1) v += __shfl_down(v, o, 64);
    __syncthreads();
    int lane = threadIdx.x & 63, w = threadIdx.x >> 6;
    if (lane == 0) s4[w] = v;
    __syncthreads();
    return s4[0] + s4[1] + s4[2] + s4[3];
}

__device__ __forceinline__ float blockMax256(float v, volatile float* s4) {
#pragma unroll
    for (int o = 32; o > 0; o >>= 1) v = fmaxf(v, __shfl_down(v, o, 64));
    __syncthreads();
    int lane = threadIdx.x & 63, w = threadIdx.x >> 6;
    if (lane == 0) s4[w] = v;
    __syncthreads();
    return fmaxf(fmaxf(s4[0], s4[1]), fmaxf(s4[2], s4[3]));
}

// 544 blocks. [0,512): min blocks — 2048 queries (8/thread) x 256 targets in
// LDS, scalar fma+min3 inner loop (v_pk_fma_f32 is HALF-RATE on CDNA4 —
// measured R1: packed rewrite regressed k_min 12->24 us; scalar is the floor).
// Each broadcast ds_read feeds 56 VALU ops -> VALU-issue-bound at ~3.5
// inst/pair, within 15% of the 3-fma/pair floor.
// [512,544): grasp/cls partial sums — independent of the min partials, so
// they hide under the 12 us min phase instead of lengthening k_reduce.
__global__ __launch_bounds__(256) void k_min(const float* __restrict__ xyz,
                                             const float* __restrict__ smp,
                                             const float* __restrict__ gp,
                                             const float* __restrict__ gg,
                                             const float* __restrict__ cp,
                                             const float* __restrict__ cg,
                                             float* __restrict__ ws) {
    __shared__ float4 tgt[TGT];
    __shared__ float s4a[4], s4b[4], s4c[4];
    const int tid = threadIdx.x;
    const int bx  = blockIdx.x;
    if (bx == 0 && tid == 0) ((unsigned*)ws)[R_CNT] = 0u;  // reset fused-final counter

    if (bx >= 512) {
        // ---- grasp / cls terms (reads only gp/gg/cp/cg) ----
        int m = (bx - 512) * 256 + tid;            // [0, 8192)
        const float* g = gp + (size_t)m * 7;
        float cxp = g[0], cyp = g[1], czp = g[2];
        float q0 = g[3], q1 = g[4], q2 = g[5], q3 = g[6];
        float invq = 1.0f / sqrtf(q0*q0 + q1*q1 + q2*q2 + q3*q3 + 1e-12f);
        const float* G = gg + (size_t)m * 16;
        float tr = G[0] + G[5] + G[10];
        float w = 0.5f * sqrtf(fmaxf(1.0f + tr, 1e-12f));
        float inv4w = 1.0f / (4.0f * w);
        float gqx = (G[9] - G[6]) * inv4w;
        float gqy = (G[2] - G[8]) * inv4w;
        float gqz = (G[4] - G[1]) * inv4w;
        float cw = cg[m];
        float dx = cxp - G[3]  + 1e-6f;
        float dy = cyp - G[7]  + 1e-6f;
        float dz = czp - G[11] + 1e-6f;
        float dist = sqrtf(dx*dx + dy*dy + dz*dz);
        float dot = (q0*w + q1*gqx + q2*gqy + q3*gqz) * invq;
        float rot = acosf(fminf(fabsf(dot), 1.0f - 1e-7f));
        float p = fminf(fmaxf(cp[m], 1e-7f), 1.0f - 1e-7f);
        float ce = cw * logf(p) + (1.0f - cw) * logf(1.0f - p);
        float s1 = blockSum256(dist * cw, s4a);
        float s2 = blockSum256(rot  * cw, s4b);
        float s3 = blockSum256(ce, s4c);
        int i = bx - 512;
        if (tid == 0) { ws[R_GST + i] = s1; ws[R_GSR + i] = s2; ws[R_GSC + i] = s3; }
        return;
    }

    const float* qptr; const float* tptr; float* outp;
    if (bx < 256) {
        // dir2: queries = xyz. per batch: 8 query-blocks x 8 target-splits.
        int b = bx >> 6, r = bx & 63, qb = r >> 3, s = r & 7;
        int gq = b * NN + qb * 2048;
        qptr = xyz + (size_t)gq * 3;
        tptr = smp + (size_t)(b * MM + s * TGT) * 3;
        outp = ws + PART2OFF + s * BN + gq;
    } else {
        // dir1: queries = smp. per batch: 1 query-block (2048=MM) x 64 splits.
        int bx2 = bx - 256;
        int b = bx2 >> 6, s = bx2 & 63;
        int gq = b * MM;
        qptr = smp + (size_t)gq * 3;
        tptr = xyz + (size_t)(b * NN + s * TGT) * 3;
        outp = ws + PART1OFF + s * BM + gq;
    }
    {   // stage: exactly one target per thread
        float x = tptr[3*tid], y = tptr[3*tid+1], z = tptr[3*tid+2];
        tgt[tid] = make_float4(-2.0f*x, -2.0f*y, -2.0f*z, x*x + y*y + z*z);
    }
    float qx[8], qy[8], qz[8], mn[8];
#pragma unroll
    for (int k = 0; k < 8; ++k) {
        int q = tid + k * 256;
        qx[k] = qptr[3*q]; qy[k] = qptr[3*q+1]; qz[k] = qptr[3*q+2];
        mn[k] = INFINITY;
    }
    __syncthreads();
#pragma unroll 2
    for (int j = 0; j < TGT; j += 2) {
        float4 ta = tgt[j], tb = tgt[j+1];
#pragma unroll
        for (int k = 0; k < 8; ++k) {
            float da = fmaf(ta.x, qx[k], fmaf(ta.y, qy[k], fmaf(ta.z, qz[k], ta.w)));
            float db = fmaf(tb.x, qx[k], fmaf(tb.y, qy[k], fmaf(tb.z, qz[k], tb.w)));
            mn[k] = fminf(mn[k], fminf(da, db));     // -> v_min3_f32
        }
    }
#pragma unroll
    for (int k = 0; k < 8; ++k) {
        int q = tid + k * 256;
        outp[q] = mn[k] + (qx[k]*qx[k] + qy[k]*qy[k] + qz[k]*qz[k]);
    }
}

// 160 blocks: [0,32) dir1 combine (1 q/thread, min over 64 splits) + sum + max;
// [32,160) dir2 combine (2 q/thread, min over 8 splits) + sum — widened from
// 64 to 128 blocks: at 128 total blocks half the CUs idled (1.8 TB/s eff).
// The LAST block to finish (device-scope counter) runs the final reduction:
// saves a dispatch. GAMMA=0.5 ALPHA=0.5 BETA=1 THETA=1.
__global__ __launch_bounds__(256) void k_reduce(const float* __restrict__ temp,
                                                float* __restrict__ ws,
                                                float* __restrict__ out) {
    __shared__ float s4a[4], s4b[4];
    __shared__ bool amLast;
    const int bx = blockIdx.x, tid = threadIdx.x;
    if (bx < 32) {
        int q = bx * 256 + tid;
        float v = INFINITY;
#pragma unroll
        for (int sp = 0; sp < S1; ++sp) v = fminf(v, ws[PART1OFF + sp * BM + q]);
        float bs = blockSum256(v, s4a);
        float bm = blockMax256(v, s4b);
        if (tid == 0) { ws[R_SUMS1 + bx] = bs; ws[R_MAXES + bx] = bm; }
    } else {
        int i = bx - 32;                  // [0,128)
        float s = 0.0f;
#pragma unroll
        for (int k = 0; k < 2; ++k) {
            int q = i * 512 + tid + k * 256;
            float v = INFINITY;
#pragma unroll
            for (int sp = 0; sp < S2; ++sp) v = fminf(v, ws[PART2OFF + sp * BN + q]);
            s += v;
        }
        float bs = blockSum256(s, s4a);
        if (tid == 0) ws[R_SUMS2 + i] = bs;
    }
    // ---- fused final: last block to arrive reduces the partials ----
    __threadfence();                               // release our stores
    if (tid == 0) {
        unsigned prev = atomicAdd((unsigned*)ws + R_CNT, 1u);
        amLast = (prev == 159u);
    }
    __syncthreads();
    if (amLast) {
        __threadfence();                           // acquire others' stores
        float a = (tid < 32) ? ws[R_SUMS1 + tid] : 0.0f;
        float f = 0.0f;
        if (tid < 4) {                             // per-batch max over its 8 block-maxes
            f = -INFINITY;
#pragma unroll
            for (int r = 0; r < 8; ++r) f = fmaxf(f, ws[R_MAXES + tid * 8 + r]);
        }
        float b = (tid < 128) ? ws[R_SUMS2 + tid] : 0.0f;
        float c = (tid < 32) ? ws[R_GST + tid] : 0.0f;
        float d = (tid < 32) ? ws[R_GSR + tid] : 0.0f;
        float e = (tid < 32) ? ws[R_GSC + tid] : 0.0f;
        float A = blockSum256(a, s4a);
        float F = blockSum256(f, s4a);
        float B = blockSum256(b, s4a);
        float C = blockSum256(c, s4a);
        float D = blockSum256(d, s4a);
        float E = blockSum256(e, s4a);
        if (tid == 0) {
            float sample = A * (1.0f / BM) + F * 0.25f + 0.5f * B * (1.0f / BN);
            float reg    = C * (1.0f / BM) + 0.5f * D * (1.0f / BM);
            float cls    = -E * (1.0f / BM);
            float t = temp[0];
            out[0] = sample + t * t + reg + cls;
        }
    }
}

extern "C" void kernel_launch(void* const* d_in, const int* in_sizes, int n_in,
                              void* d_out, int out_size, void* d_ws, size_t ws_size,
                              hipStream_t stream) {
    const float* xyz  = (const float*)d_in[0];
    const float* smp  = (const float*)d_in[1];
    const float* temp = (const float*)d_in[2];
    const float* gp   = (const float*)d_in[3];
    const float* gg   = (const float*)d_in[4];
    const float* cp   = (const float*)d_in[5];
    const float* cg   = (const float*)d_in[6];
    float* ws  = (float*)d_ws;
    float* out = (float*)d_out;

    hipLaunchKernelGGL(k_min,    dim3(544), dim3(256), 0, stream,
                       xyz, smp, gp, gg, cp, cg, ws);
    hipLaunchKernelGGL(k_reduce, dim3(160), dim3(256), 0, stream, temp, ws, out);
}

// Round 3
// 97.414 us; speedup vs baseline: 1.1238x; 1.1238x over previous
//
#include <hip/hip_runtime.h>
#include <math.h>

// Problem constants (match reference setup_inputs)
#define BB 4
#define NN 16384
#define MM 2048
#define BM (BB*MM)      // 8192  (sample queries)
#define BN (BB*NN)      // 65536 (xyz queries)

#define TGT 256         // targets per k_min block (1 KB staged -> 4 KB float4 LDS)
#define S1  64          // dir1 (smp->xyz) target splits: 64*256 = NN
#define S2  8           // dir2 (xyz->smp) target splits: 8*256  = MM

// Workspace layout (floats). Every slot plain-stored by exactly one owner
// before being read -> no init kernel, no atomics, NO device-scope fences.
// (R1/R2 lesson: last-block fusion via atomic+__threadfence cost +12 us —
// each release fence does a cross-XCD L2 writeback+drain on gfx950. The
// kernel-launch boundary provides that coherence for free.)
#define PART1OFF 0                       // [S1*BM] dir1 partial mins (incl qsq)
#define PART2OFF (S1*BM)                 // [S2*BN] dir2 partial mins (incl qsq)
#define REDOFF   (PART1OFF + S1*BM + S2*BN)
#define R_SUMS1  (REDOFF)                // [32]  per-block sums of d_smp_org
#define R_MAXES  (REDOFF+32)             // [32]  per-block maxes (8 blocks/batch)
#define R_SUMS2  (REDOFF+64)             // [128] per-block sums of d_org_smp
#define R_GST    (REDOFF+192)            // [32]  trans partial sums
#define R_GSR    (REDOFF+224)            // [32]  rot partial sums
#define R_GSC    (REDOFF+256)            // [32]  cls partial sums

__device__ __forceinline__ float blockSum256(float v, volatile float* s4) {
#pragma unroll
    for (int o = 32; o > 0; o >>= 1) v += __shfl_down(v, o, 64);
    __syncthreads();
    int lane = threadIdx.x & 63, w = threadIdx.x >> 6;
    if (lane == 0) s4[w] = v;
    __syncthreads();
    return s4[0] + s4[1] + s4[2] + s4[3];
}

__device__ __forceinline__ float blockMax256(float v, volatile float* s4) {
#pragma unroll
    for (int o = 32; o > 0; o >>= 1) v = fmaxf(v, __shfl_down(v, o, 64));
    __syncthreads();
    int lane = threadIdx.x & 63, w = threadIdx.x >> 6;
    if (lane == 0) s4[w] = v;
    __syncthreads();
    return fmaxf(fmaxf(s4[0], s4[1]), fmaxf(s4[2], s4[3]));
}

// 544 blocks. [0,512): min blocks — 2048 queries (8/thread) x 256 targets in
// LDS, scalar fma+min3 inner loop (v_pk_fma_f32 is half-rate on CDNA4 =
// issue-neutral; scalar keeps the compiler free to schedule). Each broadcast
// ds_read pair feeds 56 VALU ops -> VALU-issue-bound, within ~15% of the
// 3-fma/pair floor. [512,544): grasp/cls partial sums — independent work that
// hides under the 12 us min phase. __launch_bounds__(256,2) pins VGPR<=128 so
// the transcendental branch can't cost the min blocks their 2-waves/SIMD.
__global__ __launch_bounds__(256, 2) void k_min(const float* __restrict__ xyz,
                                                const float* __restrict__ smp,
                                                const float* __restrict__ gp,
                                                const float* __restrict__ gg,
                                                const float* __restrict__ cp,
                                                const float* __restrict__ cg,
                                                float* __restrict__ ws) {
    __shared__ float4 tgt[TGT];
    __shared__ float s4a[4], s4b[4], s4c[4];
    const int tid = threadIdx.x;
    const int bx  = blockIdx.x;

    if (bx >= 512) {
        // ---- grasp / cls terms (reads only gp/gg/cp/cg) ----
        int m = (bx - 512) * 256 + tid;            // [0, 8192)
        const float* g = gp + (size_t)m * 7;
        float cxp = g[0], cyp = g[1], czp = g[2];
        float q0 = g[3], q1 = g[4], q2 = g[5], q3 = g[6];
        float invq = 1.0f / sqrtf(q0*q0 + q1*q1 + q2*q2 + q3*q3 + 1e-12f);
        const float* G = gg + (size_t)m * 16;
        float tr = G[0] + G[5] + G[10];
        float w = 0.5f * sqrtf(fmaxf(1.0f + tr, 1e-12f));
        float inv4w = 1.0f / (4.0f * w);
        float gqx = (G[9] - G[6]) * inv4w;
        float gqy = (G[2] - G[8]) * inv4w;
        float gqz = (G[4] - G[1]) * inv4w;
        float cw = cg[m];
        float dx = cxp - G[3]  + 1e-6f;
        float dy = cyp - G[7]  + 1e-6f;
        float dz = czp - G[11] + 1e-6f;
        float dist = sqrtf(dx*dx + dy*dy + dz*dz);
        float dot = (q0*w + q1*gqx + q2*gqy + q3*gqz) * invq;
        float rot = acosf(fminf(fabsf(dot), 1.0f - 1e-7f));
        float p = fminf(fmaxf(cp[m], 1e-7f), 1.0f - 1e-7f);
        float ce = cw * logf(p) + (1.0f - cw) * logf(1.0f - p);
        float s1 = blockSum256(dist * cw, s4a);
        float s2 = blockSum256(rot  * cw, s4b);
        float s3 = blockSum256(ce, s4c);
        int i = bx - 512;
        if (tid == 0) { ws[R_GST + i] = s1; ws[R_GSR + i] = s2; ws[R_GSC + i] = s3; }
        return;
    }

    const float* qptr; const float* tptr; float* outp;
    if (bx < 256) {
        // dir2: queries = xyz. per batch: 8 query-blocks x 8 target-splits.
        int b = bx >> 6, r = bx & 63, qb = r >> 3, s = r & 7;
        int gq = b * NN + qb * 2048;
        qptr = xyz + (size_t)gq * 3;
        tptr = smp + (size_t)(b * MM + s * TGT) * 3;
        outp = ws + PART2OFF + s * BN + gq;
    } else {
        // dir1: queries = smp. per batch: 1 query-block (2048=MM) x 64 splits.
        int bx2 = bx - 256;
        int b = bx2 >> 6, s = bx2 & 63;
        int gq = b * MM;
        qptr = smp + (size_t)gq * 3;
        tptr = xyz + (size_t)(b * NN + s * TGT) * 3;
        outp = ws + PART1OFF + s * BM + gq;
    }
    {   // stage: exactly one target per thread
        float x = tptr[3*tid], y = tptr[3*tid+1], z = tptr[3*tid+2];
        tgt[tid] = make_float4(-2.0f*x, -2.0f*y, -2.0f*z, x*x + y*y + z*z);
    }
    float qx[8], qy[8], qz[8], mn[8];
#pragma unroll
    for (int k = 0; k < 8; ++k) {
        int q = tid + k * 256;
        qx[k] = qptr[3*q]; qy[k] = qptr[3*q+1]; qz[k] = qptr[3*q+2];
        mn[k] = INFINITY;
    }
    __syncthreads();
#pragma unroll 2
    for (int j = 0; j < TGT; j += 2) {
        float4 ta = tgt[j], tb = tgt[j+1];
#pragma unroll
        for (int k = 0; k < 8; ++k) {
            float da = fmaf(ta.x, qx[k], fmaf(ta.y, qy[k], fmaf(ta.z, qz[k], ta.w)));
            float db = fmaf(tb.x, qx[k], fmaf(tb.y, qy[k], fmaf(tb.z, qz[k], tb.w)));
            mn[k] = fminf(mn[k], fminf(da, db));     // -> v_min3_f32
        }
    }
#pragma unroll
    for (int k = 0; k < 8; ++k) {
        int q = tid + k * 256;
        outp[q] = mn[k] + (qx[k]*qx[k] + qy[k]*qy[k] + qz[k]*qz[k]);
    }
}

// 160 blocks: [0,32) dir1 combine (1 q/thread, min over 64 splits) + sum + max;
// [32,160) dir2 combine (2 q/thread, min over 8 splits) + sum — 128 blocks so
// all CUs participate (64 left half the chip idle). Plain per-block stores; the
// k_final dispatch boundary handles cross-XCD visibility.
__global__ __launch_bounds__(256) void k_reduce(float* __restrict__ ws) {
    __shared__ float s4a[4], s4b[4];
    const int bx = blockIdx.x, tid = threadIdx.x;
    if (bx < 32) {
        int q = bx * 256 + tid;
        float v = INFINITY;
#pragma unroll
        for (int sp = 0; sp < S1; ++sp) v = fminf(v, ws[PART1OFF + sp * BM + q]);
        float bs = blockSum256(v, s4a);
        float bm = blockMax256(v, s4b);
        if (tid == 0) { ws[R_SUMS1 + bx] = bs; ws[R_MAXES + bx] = bm; }
    } else {
        int i = bx - 32;                  // [0,128)
        float s = 0.0f;
#pragma unroll
        for (int k = 0; k < 2; ++k) {
            int q = i * 512 + tid + k * 256;
            float v = INFINITY;
#pragma unroll
            for (int sp = 0; sp < S2; ++sp) v = fminf(v, ws[PART2OFF + sp * BN + q]);
            s += v;
        }
        float bs = blockSum256(s, s4a);
        if (tid == 0) ws[R_SUMS2 + i] = bs;
    }
}

// GAMMA=0.5 ALPHA=0.5 BETA=1 THETA=1
__global__ __launch_bounds__(256) void k_final(const float* __restrict__ temp,
                                               const float* __restrict__ ws,
                                               float* __restrict__ out) {
    __shared__ float s4[4];
    const int tid = threadIdx.x;
    float a = (tid < 32) ? ws[R_SUMS1 + tid] : 0.0f;
    float f = 0.0f;
    if (tid < 4) {                         // per-batch max over its 8 block-maxes
        f = -INFINITY;
#pragma unroll
        for (int r = 0; r < 8; ++r) f = fmaxf(f, ws[R_MAXES + tid * 8 + r]);
    }
    float b = (tid < 128) ? ws[R_SUMS2 + tid] : 0.0f;
    float c = (tid < 32) ? ws[R_GST + tid] : 0.0f;
    float d = (tid < 32) ? ws[R_GSR + tid] : 0.0f;
    float e = (tid < 32) ? ws[R_GSC + tid] : 0.0f;
    float A = blockSum256(a, s4);
    float F = blockSum256(f, s4);
    float B = blockSum256(b, s4);
    float C = blockSum256(c, s4);
    float D = blockSum256(d, s4);
    float E = blockSum256(e, s4);
    if (tid == 0) {
        float sample = A * (1.0f / BM) + F * 0.25f + 0.5f * B * (1.0f / BN);
        float reg    = C * (1.0f / BM) + 0.5f * D * (1.0f / BM);
        float cls    = -E * (1.0f / BM);
        float t = temp[0];
        out[0] = sample + t * t + reg + cls;
    }
}

extern "C" void kernel_launch(void* const* d_in, const int* in_sizes, int n_in,
                              void* d_out, int out_size, void* d_ws, size_t ws_size,
                              hipStream_t stream) {
    const float* xyz  = (const float*)d_in[0];
    const float* smp  = (const float*)d_in[1];
    const float* temp = (const float*)d_in[2];
    const float* gp   = (const float*)d_in[3];
    const float* gg   = (const float*)d_in[4];
    const float* cp   = (const float*)d_in[5];
    const float* cg   = (const float*)d_in[6];
    float* ws  = (float*)d_ws;
    float* out = (float*)d_out;

    hipLaunchKernelGGL(k_min,    dim3(544), dim3(256), 0, stream,
                       xyz, smp, gp, gg, cp, cg, ws);
    hipLaunchKernelGGL(k_reduce, dim3(160), dim3(256), 0, stream, ws);
    hipLaunchKernelGGL(k_final,  dim3(1),   dim3(256), 0, stream, temp, ws, out);
}